// Round 4
// baseline (546.830 us; speedup 1.0000x reference)
//
#include <hip/hip_runtime.h>

#define H 1024
#define MMEM 4096
#define NTOK 8192
#define KTOP 64
#define FTHRESH 0.5f

typedef _Float16 half8 __attribute__((ext_vector_type(8)));  // 8 f16 in 4 VGPRs
typedef float vf4 __attribute__((ext_vector_type(4)));       // MFMA f32 acc

__device__ __forceinline__ short f2h(float x){
  union { _Float16 h; short s; } u; u.h = (_Float16)x; return u.s;
}
__device__ __forceinline__ float h2f(short s){
  union { _Float16 h; short s; } u; u.s = s; return (float)u.h;
}

// async global->LDS, 16B/lane; LDS dest is wave-uniform base + lane*16 (HW rule)
__device__ __forceinline__ void gload_lds16(const short* g, short* l){
  __builtin_amdgcn_global_load_lds(
      (const __attribute__((address_space(1))) unsigned int*)g,
      (__attribute__((address_space(3))) unsigned int*)l, 16, 0, 0);
}

// ---------------- LayerNorm + surprise; outputs fp16 norm ----------------
__global__ __launch_bounds__(256) void ln_kernel(
    const float* __restrict__ hs, const float* __restrict__ g, const float* __restrict__ be,
    short* __restrict__ n16, float* __restrict__ surprise)
{
  int row = blockIdx.x, tid = threadIdx.x;
  long base = (long)row * H;
  float4 x = ((const float4*)(hs + base))[tid];
  float s1 = x.x + x.y + x.z + x.w;
  float s2 = x.x*x.x + x.y*x.y + x.z*x.z + x.w*x.w;
  __shared__ float r1[4], r2[4], r3[4];
  int w = tid >> 6, lane = tid & 63;
  for (int o = 32; o; o >>= 1){ s1 += __shfl_down(s1, o); s2 += __shfl_down(s2, o); }
  if (lane == 0){ r1[w] = s1; r2[w] = s2; }
  __syncthreads();
  float S1 = r1[0]+r1[1]+r1[2]+r1[3];
  float S2 = r2[0]+r2[1]+r2[2]+r2[3];
  float mean = S1 * (1.0f/H);
  float var  = S2 * (1.0f/H) - mean*mean;
  float rinv = rsqrtf(var + 1e-12f);
  float4 gg = ((const float4*)g)[tid];
  float4 bb = ((const float4*)be)[tid];
  float4 n;
  n.x = (x.x-mean)*rinv*gg.x + bb.x;
  n.y = (x.y-mean)*rinv*gg.y + bb.y;
  n.z = (x.z-mean)*rinv*gg.z + bb.z;
  n.w = (x.w-mean)*rinv*gg.w + bb.w;
  float sa = fabsf(n.x)+fabsf(n.y)+fabsf(n.z)+fabsf(n.w);
  for (int o = 32; o; o >>= 1) sa += __shfl_down(sa, o);
  if (lane == 0) r3[w] = sa;
  __syncthreads();
  if (tid == 0) surprise[row] = (r3[0]+r3[1]+r3[2]+r3[3]) * (1.0f/H);
  short4 h4;
  h4.x = f2h(n.x); h4.y = f2h(n.y); h4.z = f2h(n.z); h4.w = f2h(n.w);
  ((short4*)(n16 + base))[tid] = h4;
}

// ---------------- hierarchical wave-synchronous top-K (1 barrier total) ----------------
// block 0: top-K of surprise (max, ties->lower idx). block 1: K smallest importance.
// Phase 1: each wave selects top-64 of its contiguous chunk via shfl argmax-and-clear.
// Phase 2: wave 0 merges the 4x64 candidates (global top-64 is a subset under the
// strict (val desc, idx asc) total order).
__global__ __launch_bounds__(256) void topk_kernel(
    const float* __restrict__ surprise, const float* __restrict__ imp,
    float* __restrict__ top_vals, int* __restrict__ top_idx, int* __restrict__ slots)
{
  int tid = threadIdx.x, w = tid >> 6, lane = tid & 63;
  int maxmode = (blockIdx.x == 0);
  int per = maxmode ? 32 : 16;               // elems/thread: 8192/256 or 4096/256
  const float* src = maxmode ? surprise : imp;
  int wbase = w * 64 * per;                  // wave-contiguous chunk
  float v[32];
  unsigned mask = maxmode ? 0xffffffffu : 0xffffu;
  #pragma unroll
  for (int j = 0; j < 32; ++j)
    if (j < per){ float x = src[wbase + lane + j*64]; v[j] = maxmode ? x : -x; }

  __shared__ float cv[256]; __shared__ int ci[256];

  for (int it = 0; it < KTOP; ++it){
    float best = -1e30f; int bj = -1;
    #pragma unroll
    for (int j = 0; j < 32; ++j)
      if (j < per && (mask & (1u << j)))
        if (v[j] > best){ best = v[j]; bj = j; }   // strict > keeps lowest j => lowest idx
    int bidx = (bj < 0) ? 0x7fffffff : (wbase + lane + bj*64);
    for (int o = 32; o; o >>= 1){
      float ov = __shfl_down(best, o); int oi = __shfl_down(bidx, o);
      if (ov > best || (ov == best && oi < bidx)){ best = ov; bidx = oi; }
    }
    best = __shfl(best, 0); bidx = __shfl(bidx, 0);
    if (lane == 0){ cv[w*64 + it] = best; ci[w*64 + it] = bidx; }
    int rel = bidx - wbase;
    if (rel >= 0 && rel < per*64 && (rel & 63) == lane) mask &= ~(1u << (rel >> 6));
  }
  __syncthreads();
  if (w == 0){
    float cvv[4]; int cii[4]; unsigned m4 = 0xfu;
    #pragma unroll
    for (int q = 0; q < 4; ++q){ cvv[q] = cv[q*64 + lane]; cii[q] = ci[q*64 + lane]; }
    for (int it = 0; it < KTOP; ++it){
      float best = -1e30f; int bi = 0x7fffffff;
      #pragma unroll
      for (int q = 0; q < 4; ++q)
        if ((m4 >> q) & 1u){
          if (cvv[q] > best || (cvv[q] == best && cii[q] < bi)){ best = cvv[q]; bi = cii[q]; }
        }
      for (int o = 32; o; o >>= 1){
        float ov = __shfl_down(best, o); int oi = __shfl_down(bi, o);
        if (ov > best || (ov == best && oi < bi)){ best = ov; bi = oi; }
      }
      best = __shfl(best, 0); bi = __shfl(bi, 0);
      if (lane == 0){
        if (maxmode){ top_vals[it] = best; top_idx[it] = bi; }
        else slots[it] = bi;
      }
      #pragma unroll
      for (int q = 0; q < 4; ++q)
        if (cii[q] == bi) m4 &= ~(1u << q);
    }
  }
}

// ---------------- fp32 -> fp16 convert (float4 -> short4) ----------------
__global__ __launch_bounds__(256) void tof16_kernel(const float* __restrict__ in, short* __restrict__ out)
{
  long i = (long)blockIdx.x * 256 + threadIdx.x;
  float4 x = ((const float4*)in)[i];
  short4 h;
  h.x = f2h(x.x); h.y = f2h(x.y); h.z = f2h(x.z); h.w = f2h(x.w);
  ((short4*)out)[i] = h;
}

// ---------------- Wq fp32 [H][H] -> WqT fp16 hi/lo ----------------
__global__ __launch_bounds__(256) void transpose_split_kernel(
    const float* __restrict__ in, short* __restrict__ th_, short* __restrict__ tl_)
{
  __shared__ float t[32][33];
  int c0 = blockIdx.x*32, r0 = blockIdx.y*32;
  int tid = threadIdx.x;
  for (int k = 0; k < 4; ++k){
    int i = tid + k*256; int r = i >> 5, c = i & 31;
    t[r][c] = in[(long)(r0+r)*H + c0 + c];
  }
  __syncthreads();
  for (int k = 0; k < 4; ++k){
    int i = tid + k*256; int c = i >> 5, r = i & 31;
    float x = t[r][c];
    short hh = f2h(x);
    th_[(long)(c0+c)*H + r0 + r] = hh;
    tl_[(long)(c0+c)*H + r0 + r] = f2h(x - h2f(hh));
  }
}

// ---------------- top-K memory writes: recompute LN of selected rows ----------------
__global__ __launch_bounds__(256) void update_kernel(
    const float* __restrict__ top_vals, const int* __restrict__ top_idx, const int* __restrict__ slots,
    const float* __restrict__ hs, const float* __restrict__ g, const float* __restrict__ be,
    short* __restrict__ m16)
{
  int i = blockIdx.x;
  if (top_vals[i] <= FTHRESH) return;
  int s = slots[i], r = top_idx[i];
  int tid = threadIdx.x, w = tid >> 6, lane = tid & 63;
  long base = (long)r * H;
  float4 x = ((const float4*)(hs + base))[tid];
  float s1 = x.x + x.y + x.z + x.w;
  float s2 = x.x*x.x + x.y*x.y + x.z*x.z + x.w*x.w;
  __shared__ float r1[4], r2[4];
  for (int o = 32; o; o >>= 1){ s1 += __shfl_down(s1, o); s2 += __shfl_down(s2, o); }
  if (lane == 0){ r1[w] = s1; r2[w] = s2; }
  __syncthreads();
  float S1 = r1[0]+r1[1]+r1[2]+r1[3];
  float S2 = r2[0]+r2[1]+r2[2]+r2[3];
  float mean = S1 * (1.0f/H);
  float var  = S2 * (1.0f/H) - mean*mean;
  float rinv = rsqrtf(var + 1e-12f);
  float4 gg = ((const float4*)g)[tid];
  float4 bb = ((const float4*)be)[tid];
  short4 h4;
  h4.x = f2h((x.x-mean)*rinv*gg.x + bb.x);
  h4.y = f2h((x.y-mean)*rinv*gg.y + bb.y);
  h4.z = f2h((x.z-mean)*rinv*gg.z + bb.z);
  h4.w = f2h((x.w-mean)*rinv*gg.w + bb.w);
  ((short4*)(m16 + (long)s*H))[tid] = h4;
}

// ---------------- fp16 transpose m16 [MMEM][H] -> memT [H][MMEM] ----------------
__global__ __launch_bounds__(256) void transpose_f16_kernel(const short* __restrict__ in, short* __restrict__ out)
{
  __shared__ short t[64][65];
  int r0 = blockIdx.y*64, c0 = blockIdx.x*64;
  int tid = threadIdx.x;
  for (int k = 0; k < 16; ++k){
    int i = tid + k*256; int r = i >> 6, c = i & 63;
    t[r][c] = in[(long)(r0+r)*H + c0 + c];
  }
  __syncthreads();
  for (int k = 0; k < 16; ++k){
    int i = tid + k*256; int c = i >> 6, r = i & 63;
    out[(long)(c0+c)*MMEM + r0 + r] = t[r][c];
  }
}

// ---------------- biasM[m] = bq . mem_upd[m] ----------------
__global__ __launch_bounds__(256) void bias_kernel(
    const float* __restrict__ bq, const short* __restrict__ m16, float* __restrict__ biasM)
{
  int tid = threadIdx.x, w = tid >> 6, lane = tid & 63;
  int m = blockIdx.x*4 + w;
  const short* ph = m16 + (long)m*H;
  float s = 0.f;
  for (int j = 0; j < 16; ++j){
    int h = lane + j*64;
    s += bq[h] * h2f(ph[h]);
  }
  for (int o = 32; o; o >>= 1) s += __shfl_down(s, o);
  if (lane == 0) biasM[m] = s;
}

// ---------------- 128x128-tile fp16 GEMM: C[M][N] = A[M][K] * B[N][K]^T ----------------
// m97 recipe (BK=64, global_load_lds w16, 2 barriers/K-block) + XOR-8 LDS swizzle
// (chunk pos ^= row&7 on global source AND ds_read side -> conflicts measured 0).
// SPLIT: 0 = A,B single f16 (1 MFMA); 2 = A single, B fp16 hi/lo (2 MFMA compensated).
// MODE 0: C -> fp16 hi/lo.  1: C+biasN -> fp16.  2: C -> fp16.  3: C+resid+biasN -> fp32.
template<int SPLIT, int MODE>
__global__ __launch_bounds__(256) void gemm128(
    const short* __restrict__ A,
    const short* __restrict__ Bh, const short* __restrict__ Bl,
    int K, int N,
    short* __restrict__ O1, short* __restrict__ O2,
    float* __restrict__ Of, const float* __restrict__ resid, const float* __restrict__ biasN)
{
  __shared__ short sA[128*64];
  __shared__ short sBh[128*64];
  __shared__ short sBl[SPLIT ? 128*64 : 64];
  int tid = threadIdx.x, w = tid >> 6, lane = tid & 63, ln = lane & 15, quad = lane >> 4;
  int wr = w >> 1, wc = w & 1;
  long m0 = (long)blockIdx.y * 128, n0 = (long)blockIdx.x * 128;
  long Kl = K;
  vf4 acc[4][4];
  #pragma unroll
  for (int i = 0; i < 4; ++i) for (int j = 0; j < 4; ++j) for (int r = 0; r < 4; ++r) acc[i][j][r] = 0.0f;

  for (long kk = 0; kk < Kl; kk += 64){
    #pragma unroll
    for (int j = 0; j < 4; ++j){
      int f = (w*4 + j)*64 + lane;            // 16B-chunk id in [0,1024)
      int row = f >> 3, c8 = f & 7;
      long go = kk + (long)((c8 ^ (row & 7)) * 8);   // XOR-swizzled source chunk
      gload_lds16(A  + (m0+row)*Kl + go, sA  + (w*4+j)*512);
      gload_lds16(Bh + (n0+row)*Kl + go, sBh + (w*4+j)*512);
      if (SPLIT) gload_lds16(Bl + (n0+row)*Kl + go, sBl + (w*4+j)*512);
    }
    __syncthreads();
    #pragma unroll
    for (int ks = 0; ks < 64; ks += 32){
      int cbase = (ks >> 3) + quad;
      half8 bh[4], bl[4];
      #pragma unroll
      for (int j = 0; j < 4; ++j){
        int rb = wc*64 + j*16 + ln;
        int cb = cbase ^ (rb & 7);
        bh[j] = *(const half8*)&sBh[rb*64 + cb*8];
        if (SPLIT) bl[j] = *(const half8*)&sBl[rb*64 + cb*8];
      }
      #pragma unroll
      for (int i = 0; i < 4; ++i){
        int ra = wr*64 + i*16 + ln;
        int ca = cbase ^ (ra & 7);
        half8 a = *(const half8*)&sA[ra*64 + ca*8];
        #pragma unroll
        for (int j = 0; j < 4; ++j){
          acc[i][j] = __builtin_amdgcn_mfma_f32_16x16x32_f16(a, bh[j], acc[i][j], 0, 0, 0);
          if (SPLIT)
            acc[i][j] = __builtin_amdgcn_mfma_f32_16x16x32_f16(a, bl[j], acc[i][j], 0, 0, 0);
        }
      }
    }
    __syncthreads();
  }

  #pragma unroll
  for (int i = 0; i < 4; ++i){
    #pragma unroll
    for (int j = 0; j < 4; ++j){
      #pragma unroll
      for (int r = 0; r < 4; ++r){
        long row = m0 + wr*64 + i*16 + quad*4 + r;   // C/D: row=quad*4+reg, col=lane&15
        long col = n0 + wc*64 + j*16 + ln;
        float v = acc[i][j][r];
        if (MODE == 0){
          short hh = f2h(v);
          O1[row*(long)N + col] = hh;
          O2[row*(long)N + col] = f2h(v - h2f(hh));
        } else if (MODE == 1){
          O1[row*(long)N + col] = f2h(v + biasN[col]);
        } else if (MODE == 2){
          O1[row*(long)N + col] = f2h(v);
        } else {
          Of[row*(long)N + col] = v + resid[row*(long)N + col] + biasN[col];
        }
      }
    }
  }
}

// ---------------- row softmax in-place: sim fp16 [NTOK][MMEM] -> P fp16 ----------------
__global__ __launch_bounds__(256) void softmax_kernel(short* __restrict__ simP)
{
  long row = blockIdx.x;
  int tid = threadIdx.x, w = tid >> 6, lane = tid & 63;
  half8* ptr = (half8*)(simP + row*MMEM);
  float xf[16];
  float mx = -1e30f;
  #pragma unroll
  for (int j = 0; j < 2; ++j){
    half8 x = ptr[tid + j*256];
    #pragma unroll
    for (int e = 0; e < 8; ++e){ float f = (float)x[e]; xf[j*8+e] = f; mx = fmaxf(mx, f); }
  }
  for (int o = 32; o; o >>= 1) mx = fmaxf(mx, __shfl_xor(mx, o));
  __shared__ float rmax[4], rsum[4];
  if (lane == 0) rmax[w] = mx;
  __syncthreads();
  mx = fmaxf(fmaxf(rmax[0], rmax[1]), fmaxf(rmax[2], rmax[3]));
  float p[16], s = 0.f;
  #pragma unroll
  for (int k = 0; k < 16; ++k){ p[k] = __expf(xf[k] - mx); s += p[k]; }
  for (int o = 32; o; o >>= 1) s += __shfl_xor(s, o);
  if (lane == 0) rsum[w] = s;
  __syncthreads();
  float inv = 1.0f / (rsum[0]+rsum[1]+rsum[2]+rsum[3]);
  #pragma unroll
  for (int j = 0; j < 2; ++j){
    half8 o8;
    #pragma unroll
    for (int e = 0; e < 8; ++e) o8[e] = (_Float16)(p[j*8+e] * inv);
    ptr[tid + j*256] = o8;
  }
}

extern "C" void kernel_launch(void* const* d_in, const int* in_sizes, int n_in,
                              void* d_out, int out_size, void* d_ws, size_t ws_size,
                              hipStream_t stream)
{
  const float* hs  = (const float*)d_in[0];
  const float* gam = (const float*)d_in[1];
  const float* bet = (const float*)d_in[2];
  const float* Wq  = (const float*)d_in[3];
  const float* bq  = (const float*)d_in[4];
  const float* Wo  = (const float*)d_in[5];
  const float* bo  = (const float*)d_in[6];
  const float* mem = (const float*)d_in[7];
  const float* imp = (const float*)d_in[8];
  float* out = (float*)d_out;

  char* ws = (char*)d_ws;
  short* n16   = (short*)(ws);                   // [0,16)   fp16 norm
  short* w2h   = (short*)(ws + (16ull<<20));     // [16,24)  W2 fp16 hi
  short* w2l   = (short*)(ws + (24ull<<20));     // [24,32)  W2 fp16 lo
  short* memT  = (short*)(ws + (32ull<<20));     // [32,40)  mem_upd^T fp16
  short* simP  = (short*)(ws + (40ull<<20));     // [40,104) fp16 logits, softmax in-place -> P
  short* retr  = (short*)(ws + (104ull<<20));    // [104,120)
  short* m16   = (short*)(ws + (120ull<<20));    // [120,128) fp16 mem (patched)
  short* wqt_h = (short*)(ws + (128ull<<20));    // [128,130)
  short* wqt_l = (short*)(ws + (130ull<<20));    // [130,132)
  short* wo16  = (short*)(ws + (132ull<<20));    // [132,134)
  char*  tail  = ws + (134ull<<20);
  float* biasM    = (float*)tail;
  float* surprise = (float*)(tail + (64<<10));
  float* top_vals = (float*)(tail + (128<<10));
  int*   top_idx  = (int*)  (tail + (129<<10));
  int*   slots    = (int*)  (tail + (130<<10));

  ln_kernel<<<NTOK, 256, 0, stream>>>(hs, gam, bet, n16, surprise);
  topk_kernel<<<2, 256, 0, stream>>>(surprise, imp, top_vals, top_idx, slots);
  tof16_kernel<<<4096, 256, 0, stream>>>(mem, m16);                         // mem -> fp16
  transpose_split_kernel<<<dim3(32,32), 256, 0, stream>>>(Wq, wqt_h, wqt_l);
  tof16_kernel<<<1024, 256, 0, stream>>>(Wo, wo16);
  update_kernel<<<KTOP, 256, 0, stream>>>(top_vals, top_idx, slots, hs, gam, bet, m16);
  transpose_f16_kernel<<<dim3(16,64), 256, 0, stream>>>(m16, memT);
  bias_kernel<<<1024, 256, 0, stream>>>(bq, m16, biasM);
  // W2 = mem_upd @ Wq  (A single f16, B split f16 hi/lo), out fp16 hi/lo
  gemm128<2,0><<<dim3(8,32), 256, 0, stream>>>(
      m16, wqt_h, wqt_l, H, H, w2h, w2l, nullptr, nullptr, nullptr);
  // sim = norm @ W2^T + biasM  (A single f16, B split), out fp16
  gemm128<2,1><<<dim3(32,64), 256, 0, stream>>>(
      n16, w2h, w2l, H, MMEM, simP, nullptr, nullptr, nullptr, biasM);
  // softmax rows in-place -> P fp16 (normalized)
  softmax_kernel<<<NTOK, 256, 0, stream>>>(simP);
  // retr = P @ memT^T  (plain f16)
  gemm128<0,2><<<dim3(8,64), 256, 0, stream>>>(
      simP, memT, memT, MMEM, H, retr, nullptr, nullptr, nullptr, nullptr);
  // out = hidden + retr @ Wo^T + bo
  gemm128<0,3><<<dim3(8,64), 256, 0, stream>>>(
      retr, wo16, wo16, H, H, nullptr, nullptr, out, hs, bo);
}

// Round 6
// 503.046 us; speedup vs baseline: 1.0870x; 1.0870x over previous
//
#include <hip/hip_runtime.h>

#define H 1024
#define MMEM 4096
#define NTOK 8192
#define KTOP 64
#define FTHRESH 0.5f

typedef _Float16 half8 __attribute__((ext_vector_type(8)));  // 8 f16 in 4 VGPRs
typedef float vf4 __attribute__((ext_vector_type(4)));       // MFMA f32 acc

__device__ __forceinline__ short f2h(float x){
  union { _Float16 h; short s; } u; u.h = (_Float16)x; return u.s;
}
__device__ __forceinline__ float h2f(short s){
  union { _Float16 h; short s; } u; u.s = s; return (float)u.h;
}

// async global->LDS, 16B/lane; LDS dest is wave-uniform base + lane*16 (HW rule)
__device__ __forceinline__ void gload_lds16(const short* g, short* l){
  __builtin_amdgcn_global_load_lds(
      (const __attribute__((address_space(1))) unsigned int*)g,
      (__attribute__((address_space(3))) unsigned int*)l, 16, 0, 0);
}

// ---------------- LayerNorm + surprise; outputs fp16 norm ----------------
__global__ __launch_bounds__(256) void ln_kernel(
    const float* __restrict__ hs, const float* __restrict__ g, const float* __restrict__ be,
    short* __restrict__ n16, float* __restrict__ surprise)
{
  int row = blockIdx.x, tid = threadIdx.x;
  long base = (long)row * H;
  float4 x = ((const float4*)(hs + base))[tid];
  float s1 = x.x + x.y + x.z + x.w;
  float s2 = x.x*x.x + x.y*x.y + x.z*x.z + x.w*x.w;
  __shared__ float r1[4], r2[4], r3[4];
  int w = tid >> 6, lane = tid & 63;
  for (int o = 32; o; o >>= 1){ s1 += __shfl_down(s1, o); s2 += __shfl_down(s2, o); }
  if (lane == 0){ r1[w] = s1; r2[w] = s2; }
  __syncthreads();
  float S1 = r1[0]+r1[1]+r1[2]+r1[3];
  float S2 = r2[0]+r2[1]+r2[2]+r2[3];
  float mean = S1 * (1.0f/H);
  float var  = S2 * (1.0f/H) - mean*mean;
  float rinv = rsqrtf(var + 1e-12f);
  float4 gg = ((const float4*)g)[tid];
  float4 bb = ((const float4*)be)[tid];
  float4 n;
  n.x = (x.x-mean)*rinv*gg.x + bb.x;
  n.y = (x.y-mean)*rinv*gg.y + bb.y;
  n.z = (x.z-mean)*rinv*gg.z + bb.z;
  n.w = (x.w-mean)*rinv*gg.w + bb.w;
  float sa = fabsf(n.x)+fabsf(n.y)+fabsf(n.z)+fabsf(n.w);
  for (int o = 32; o; o >>= 1) sa += __shfl_down(sa, o);
  if (lane == 0) r3[w] = sa;
  __syncthreads();
  if (tid == 0) surprise[row] = (r3[0]+r3[1]+r3[2]+r3[3]) * (1.0f/H);
  short4 h4;
  h4.x = f2h(n.x); h4.y = f2h(n.y); h4.z = f2h(n.z); h4.w = f2h(n.w);
  ((short4*)(n16 + base))[tid] = h4;
}

// ---------------- hierarchical wave-synchronous top-K (1 barrier) ----------------
__global__ __launch_bounds__(256) void topk_kernel(
    const float* __restrict__ surprise, const float* __restrict__ imp,
    float* __restrict__ top_vals, int* __restrict__ top_idx, int* __restrict__ slots)
{
  int tid = threadIdx.x, w = tid >> 6, lane = tid & 63;
  int maxmode = (blockIdx.x == 0);
  int per = maxmode ? 32 : 16;               // elems/thread: 8192/256 or 4096/256
  const float* src = maxmode ? surprise : imp;
  int wbase = w * 64 * per;                  // wave-contiguous chunk
  float v[32];
  unsigned mask = maxmode ? 0xffffffffu : 0xffffu;
  #pragma unroll
  for (int j = 0; j < 32; ++j)
    if (j < per){ float x = src[wbase + lane + j*64]; v[j] = maxmode ? x : -x; }

  __shared__ float cv[256]; __shared__ int ci[256];

  for (int it = 0; it < KTOP; ++it){
    float best = -1e30f; int bj = -1;
    #pragma unroll
    for (int j = 0; j < 32; ++j)
      if (j < per && (mask & (1u << j)))
        if (v[j] > best){ best = v[j]; bj = j; }   // strict > keeps lowest j => lowest idx
    int bidx = (bj < 0) ? 0x7fffffff : (wbase + lane + bj*64);
    for (int o = 32; o; o >>= 1){
      float ov = __shfl_down(best, o); int oi = __shfl_down(bidx, o);
      if (ov > best || (ov == best && oi < bidx)){ best = ov; bidx = oi; }
    }
    best = __shfl(best, 0); bidx = __shfl(bidx, 0);
    if (lane == 0){ cv[w*64 + it] = best; ci[w*64 + it] = bidx; }
    int rel = bidx - wbase;
    if (rel >= 0 && rel < per*64 && (rel & 63) == lane) mask &= ~(1u << (rel >> 6));
  }
  __syncthreads();
  if (w == 0){
    float cvv[4]; int cii[4]; unsigned m4 = 0xfu;
    #pragma unroll
    for (int q = 0; q < 4; ++q){ cvv[q] = cv[q*64 + lane]; cii[q] = ci[q*64 + lane]; }
    for (int it = 0; it < KTOP; ++it){
      float best = -1e30f; int bi = 0x7fffffff;
      #pragma unroll
      for (int q = 0; q < 4; ++q)
        if ((m4 >> q) & 1u){
          if (cvv[q] > best || (cvv[q] == best && cii[q] < bi)){ best = cvv[q]; bi = cii[q]; }
        }
      for (int o = 32; o; o >>= 1){
        float ov = __shfl_down(best, o); int oi = __shfl_down(bi, o);
        if (ov > best || (ov == best && oi < bi)){ best = ov; bi = oi; }
      }
      best = __shfl(best, 0); bi = __shfl(bi, 0);
      if (lane == 0){
        if (maxmode){ top_vals[it] = best; top_idx[it] = bi; }
        else slots[it] = bi;
      }
      #pragma unroll
      for (int q = 0; q < 4; ++q)
        if (cii[q] == bi) m4 &= ~(1u << q);
    }
  }
}

// ---------------- fused prep: mem->m16+memT, Wq->hi/lo split (as-is layout), Wo->fp16 ----------------
__global__ __launch_bounds__(256) void prep_all_kernel(
    const float* __restrict__ mem, const float* __restrict__ Wq, const float* __restrict__ Wo,
    short* __restrict__ m16, short* __restrict__ memT,
    short* __restrict__ wq_h, short* __restrict__ wq_l, short* __restrict__ wo16)
{
  __shared__ __align__(16) short t[64][66];
  int b = blockIdx.x, tid = threadIdx.x;
  if (b < 1024){
    // mem fp32 64x64 tile -> m16 (row-major) + memT (transposed)
    int r0 = (b >> 4) * 64, c0 = (b & 15) * 64;
    #pragma unroll
    for (int k = 0; k < 4; ++k){
      int idx = k*256 + tid;
      int r = idx >> 4, c4 = (idx & 15) * 4;
      float4 x = *(const float4*)&mem[(long)(r0+r)*H + c0 + c4];
      short4 h;
      h.x = f2h(x.x); h.y = f2h(x.y); h.z = f2h(x.z); h.w = f2h(x.w);
      *(short4*)&m16[(long)(r0+r)*H + c0 + c4] = h;
      t[r][c4] = h.x; t[r][c4+1] = h.y; t[r][c4+2] = h.z; t[r][c4+3] = h.w;
    }
    __syncthreads();
    #pragma unroll
    for (int k = 0; k < 4; ++k){
      int idx = k*256 + tid;
      int c = idx >> 4, r4 = (idx & 15) * 4;
      short4 h;
      h.x = t[r4][c]; h.y = t[r4+1][c]; h.z = t[r4+2][c]; h.w = t[r4+3][c];
      *(short4*)&memT[(long)(c0+c)*MMEM + r0 + r4] = h;
    }
  } else if (b < 2048){
    // Wq elementwise fp16 hi/lo split, native [o][h] layout (B-operand of Q GEMM
    // contracts over its 2nd index = h, matching einsum "bsh,oh->bso")
    long i = (long)(b - 1024) * 256 + tid;
    float4 x = ((const float4*)Wq)[i];
    short4 h, l;
    h.x = f2h(x.x); l.x = f2h(x.x - h2f(h.x));
    h.y = f2h(x.y); l.y = f2h(x.y - h2f(h.y));
    h.z = f2h(x.z); l.z = f2h(x.z - h2f(h.z));
    h.w = f2h(x.w); l.w = f2h(x.w - h2f(h.w));
    ((short4*)wq_h)[i] = h;
    ((short4*)wq_l)[i] = l;
  } else {
    long i = (long)(b - 2048) * 256 + tid;
    float4 x = ((const float4*)Wo)[i];
    short4 h;
    h.x = f2h(x.x); h.y = f2h(x.y); h.z = f2h(x.z); h.w = f2h(x.w);
    ((short4*)wo16)[i] = h;
  }
}

// ---------------- top-K writes: recompute LN of selected rows, patch m16 + memT ----------------
__global__ __launch_bounds__(256) void update_kernel(
    const float* __restrict__ top_vals, const int* __restrict__ top_idx, const int* __restrict__ slots,
    const float* __restrict__ hs, const float* __restrict__ g, const float* __restrict__ be,
    short* __restrict__ m16, short* __restrict__ memT)
{
  int i = blockIdx.x;
  if (top_vals[i] <= FTHRESH) return;
  int s = slots[i], r = top_idx[i];
  int tid = threadIdx.x, w = tid >> 6, lane = tid & 63;
  long base = (long)r * H;
  float4 x = ((const float4*)(hs + base))[tid];
  float s1 = x.x + x.y + x.z + x.w;
  float s2 = x.x*x.x + x.y*x.y + x.z*x.z + x.w*x.w;
  __shared__ float r1[4], r2[4];
  for (int o = 32; o; o >>= 1){ s1 += __shfl_down(s1, o); s2 += __shfl_down(s2, o); }
  if (lane == 0){ r1[w] = s1; r2[w] = s2; }
  __syncthreads();
  float S1 = r1[0]+r1[1]+r1[2]+r1[3];
  float S2 = r2[0]+r2[1]+r2[2]+r2[3];
  float mean = S1 * (1.0f/H);
  float var  = S2 * (1.0f/H) - mean*mean;
  float rinv = rsqrtf(var + 1e-12f);
  float4 gg = ((const float4*)g)[tid];
  float4 bb = ((const float4*)be)[tid];
  short4 h4;
  h4.x = f2h((x.x-mean)*rinv*gg.x + bb.x);
  h4.y = f2h((x.y-mean)*rinv*gg.y + bb.y);
  h4.z = f2h((x.z-mean)*rinv*gg.z + bb.z);
  h4.w = f2h((x.w-mean)*rinv*gg.w + bb.w);
  ((short4*)(m16 + (long)s*H))[tid] = h4;
  long c4 = (long)tid * 4;
  memT[(c4+0)*MMEM + s] = h4.x;
  memT[(c4+1)*MMEM + s] = h4.y;
  memT[(c4+2)*MMEM + s] = h4.z;
  memT[(c4+3)*MMEM + s] = h4.w;
}

// ---------------- biasM[m] = bq . mem_upd[m] (reads patched m16) ----------------
__global__ __launch_bounds__(256) void bias_kernel(
    const float* __restrict__ bq, const short* __restrict__ m16, float* __restrict__ biasM)
{
  int tid = threadIdx.x, w = tid >> 6, lane = tid & 63;
  int m = blockIdx.x*4 + w;
  const short* ph = m16 + (long)m*H;
  float s = 0.f;
  for (int j = 0; j < 16; ++j){
    int h = lane + j*64;
    s += bq[h] * h2f(ph[h]);
  }
  for (int o = 32; o; o >>= 1) s += __shfl_down(s, o);
  if (lane == 0) biasM[m] = s;
}

// ---------------- 128x128-tile fp16 GEMM: C[M][N] = A[M][K] * B[N][K]^T ----------------
// m97 recipe (BK=64, global_load_lds w16, 2 barriers/K-block) + XOR-8 LDS swizzle
// (chunk pos ^= row&7 on global source AND ds_read side -> conflicts measured 0).
// SPLIT: 0 = A,B single f16 (1 MFMA); 2 = A single, B fp16 hi/lo (2 MFMA compensated).
// MODE 1: C+biasN -> fp16.  2: C -> fp16.  3: C+resid+biasN -> fp32.
template<int SPLIT, int MODE>
__global__ __launch_bounds__(256) void gemm128(
    const short* __restrict__ A,
    const short* __restrict__ Bh, const short* __restrict__ Bl,
    int K, int N,
    short* __restrict__ O1,
    float* __restrict__ Of, const float* __restrict__ resid, const float* __restrict__ biasN)
{
  __shared__ short sA[128*64];
  __shared__ short sBh[128*64];
  __shared__ short sBl[SPLIT ? 128*64 : 64];
  int tid = threadIdx.x, w = tid >> 6, lane = tid & 63, ln = lane & 15, quad = lane >> 4;
  int wr = w >> 1, wc = w & 1;
  long m0 = (long)blockIdx.y * 128, n0 = (long)blockIdx.x * 128;
  long Kl = K;
  vf4 acc[4][4];
  #pragma unroll
  for (int i = 0; i < 4; ++i) for (int j = 0; j < 4; ++j) for (int r = 0; r < 4; ++r) acc[i][j][r] = 0.0f;

  for (long kk = 0; kk < Kl; kk += 64){
    #pragma unroll
    for (int j = 0; j < 4; ++j){
      int f = (w*4 + j)*64 + lane;            // 16B-chunk id in [0,1024)
      int row = f >> 3, c8 = f & 7;
      long go = kk + (long)((c8 ^ (row & 7)) * 8);   // XOR-swizzled source chunk
      gload_lds16(A  + (m0+row)*Kl + go, sA  + (w*4+j)*512);
      gload_lds16(Bh + (n0+row)*Kl + go, sBh + (w*4+j)*512);
      if (SPLIT) gload_lds16(Bl + (n0+row)*Kl + go, sBl + (w*4+j)*512);
    }
    __syncthreads();
    #pragma unroll
    for (int ks = 0; ks < 64; ks += 32){
      int cbase = (ks >> 3) + quad;
      half8 bh[4], bl[4];
      #pragma unroll
      for (int j = 0; j < 4; ++j){
        int rb = wc*64 + j*16 + ln;
        int cb = cbase ^ (rb & 7);
        bh[j] = *(const half8*)&sBh[rb*64 + cb*8];
        if (SPLIT) bl[j] = *(const half8*)&sBl[rb*64 + cb*8];
      }
      #pragma unroll
      for (int i = 0; i < 4; ++i){
        int ra = wr*64 + i*16 + ln;
        int ca = cbase ^ (ra & 7);
        half8 a = *(const half8*)&sA[ra*64 + ca*8];
        #pragma unroll
        for (int j = 0; j < 4; ++j){
          acc[i][j] = __builtin_amdgcn_mfma_f32_16x16x32_f16(a, bh[j], acc[i][j], 0, 0, 0);
          if (SPLIT)
            acc[i][j] = __builtin_amdgcn_mfma_f32_16x16x32_f16(a, bl[j], acc[i][j], 0, 0, 0);
        }
      }
    }
    __syncthreads();
  }

  #pragma unroll
  for (int i = 0; i < 4; ++i){
    #pragma unroll
    for (int j = 0; j < 4; ++j){
      #pragma unroll
      for (int r = 0; r < 4; ++r){
        long row = m0 + wr*64 + i*16 + quad*4 + r;   // C/D: row=quad*4+reg, col=lane&15
        long col = n0 + wc*64 + j*16 + ln;
        float v = acc[i][j][r];
        if (MODE == 1){
          O1[row*(long)N + col] = f2h(v + biasN[col]);
        } else if (MODE == 2){
          O1[row*(long)N + col] = f2h(v);
        } else {
          Of[row*(long)N + col] = v + resid[row*(long)N + col] + biasN[col];
        }
      }
    }
  }
}

// ---------------- row softmax in-place: sim fp16 [NTOK][MMEM] -> P fp16 ----------------
__global__ __launch_bounds__(256) void softmax_kernel(short* __restrict__ simP)
{
  long row = blockIdx.x;
  int tid = threadIdx.x, w = tid >> 6, lane = tid & 63;
  half8* ptr = (half8*)(simP + row*MMEM);
  float xf[16];
  float mx = -1e30f;
  #pragma unroll
  for (int j = 0; j < 2; ++j){
    half8 x = ptr[tid + j*256];
    #pragma unroll
    for (int e = 0; e < 8; ++e){ float f = (float)x[e]; xf[j*8+e] = f; mx = fmaxf(mx, f); }
  }
  for (int o = 32; o; o >>= 1) mx = fmaxf(mx, __shfl_xor(mx, o));
  __shared__ float rmax[4], rsum[4];
  if (lane == 0) rmax[w] = mx;
  __syncthreads();
  mx = fmaxf(fmaxf(rmax[0], rmax[1]), fmaxf(rmax[2], rmax[3]));
  float p[16], s = 0.f;
  #pragma unroll
  for (int k = 0; k < 16; ++k){ p[k] = __expf(xf[k] - mx); s += p[k]; }
  for (int o = 32; o; o >>= 1) s += __shfl_xor(s, o);
  if (lane == 0) rsum[w] = s;
  __syncthreads();
  float inv = 1.0f / (rsum[0]+rsum[1]+rsum[2]+rsum[3]);
  #pragma unroll
  for (int j = 0; j < 2; ++j){
    half8 o8;
    #pragma unroll
    for (int e = 0; e < 8; ++e) o8[e] = (_Float16)(p[j*8+e] * inv);
    ptr[tid + j*256] = o8;
  }
}

extern "C" void kernel_launch(void* const* d_in, const int* in_sizes, int n_in,
                              void* d_out, int out_size, void* d_ws, size_t ws_size,
                              hipStream_t stream)
{
  const float* hs  = (const float*)d_in[0];
  const float* gam = (const float*)d_in[1];
  const float* bet = (const float*)d_in[2];
  const float* Wq  = (const float*)d_in[3];
  const float* bq  = (const float*)d_in[4];
  const float* Wo  = (const float*)d_in[5];
  const float* bo  = (const float*)d_in[6];
  const float* mem = (const float*)d_in[7];
  const float* imp = (const float*)d_in[8];
  float* out = (float*)d_out;

  char* ws = (char*)d_ws;
  short* n16   = (short*)(ws);                   // [0,16)   fp16 norm
  short* q16   = (short*)(ws + (16ull<<20));     // [16,32)  fp16 Q = norm@Wq^T
  short* m16   = (short*)(ws + (32ull<<20));     // [32,40)  fp16 mem (patched)
  short* memT  = (short*)(ws + (40ull<<20));     // [40,48)  mem_upd^T fp16 (patched)
  short* simP  = (short*)(ws + (48ull<<20));     // [48,112) fp16 logits, softmax in-place -> P
  short* retr  = (short*)(ws + (112ull<<20));    // [112,128)
  short* wq_h  = (short*)(ws + (128ull<<20));    // [128,130) Wq fp16 hi, native [o][h]
  short* wq_l  = (short*)(ws + (130ull<<20));    // [130,132) Wq fp16 lo
  short* wo16  = (short*)(ws + (132ull<<20));    // [132,134)
  char*  tail  = ws + (134ull<<20);
  float* biasM    = (float*)tail;
  float* surprise = (float*)(tail + (64<<10));
  float* top_vals = (float*)(tail + (128<<10));
  int*   top_idx  = (int*)  (tail + (129<<10));
  int*   slots    = (int*)  (tail + (130<<10));

  ln_kernel<<<NTOK, 256, 0, stream>>>(hs, gam, bet, n16, surprise);
  topk_kernel<<<2, 256, 0, stream>>>(surprise, imp, top_vals, top_idx, slots);
  prep_all_kernel<<<3072, 256, 0, stream>>>(mem, Wq, Wo, m16, memT, wq_h, wq_l, wo16);
  update_kernel<<<KTOP, 256, 0, stream>>>(top_vals, top_idx, slots, hs, gam, bet, m16, memT);
  bias_kernel<<<1024, 256, 0, stream>>>(bq, m16, biasM);
  // Q = norm @ Wq^T  (B = Wq native layout, split hi/lo), out fp16
  gemm128<2,2><<<dim3(8,64), 256, 0, stream>>>(
      n16, wq_h, wq_l, H, H, q16, nullptr, nullptr, nullptr);
  // sim = Q @ m16^T + biasM  (plain f16, 1 MFMA/elem), out fp16
  gemm128<0,1><<<dim3(32,64), 256, 0, stream>>>(
      q16, m16, m16, H, MMEM, simP, nullptr, nullptr, biasM);
  // softmax rows in-place -> P fp16 (normalized)
  softmax_kernel<<<NTOK, 256, 0, stream>>>(simP);
  // retr = P @ memT^T  (plain f16)
  gemm128<0,2><<<dim3(8,64), 256, 0, stream>>>(
      simP, memT, memT, MMEM, H, retr, nullptr, nullptr, nullptr);
  // out = hidden + retr @ Wo^T + bo
  gemm128<0,3><<<dim3(8,64), 256, 0, stream>>>(
      retr, wo16, wo16, H, H, nullptr, out, hs, bo);
}

// Round 7
// 446.173 us; speedup vs baseline: 1.2256x; 1.1275x over previous
//
#include <hip/hip_runtime.h>

#define H 1024
#define MMEM 4096
#define NTOK 8192
#define KTOP 64
#define FTHRESH 0.5f

typedef _Float16 half8 __attribute__((ext_vector_type(8)));  // 8 f16 in 4 VGPRs
typedef float vf4 __attribute__((ext_vector_type(4)));       // MFMA f32 acc

__device__ __forceinline__ short f2h(float x){
  union { _Float16 h; short s; } u; u.h = (_Float16)x; return u.s;
}
__device__ __forceinline__ float h2f(short s){
  union { _Float16 h; short s; } u; u.s = s; return (float)u.h;
}
// order-preserving float->uint32 key (monotone increasing)
__device__ __forceinline__ unsigned fkey_of(float x){
  unsigned u = __float_as_uint(x);
  return (u & 0x80000000u) ? ~u : (u | 0x80000000u);
}
__device__ __forceinline__ float val_of(unsigned k){
  unsigned u = (k & 0x80000000u) ? (k & 0x7fffffffu) : ~k;
  return __uint_as_float(u);
}

// async global->LDS, 16B/lane; LDS dest is wave-uniform base + lane*16 (HW rule)
__device__ __forceinline__ void gload_lds16(const short* g, short* l){
  __builtin_amdgcn_global_load_lds(
      (const __attribute__((address_space(1))) unsigned int*)g,
      (__attribute__((address_space(3))) unsigned int*)l, 16, 0, 0);
}

// ---------------- LayerNorm + surprise; outputs fp16 norm ----------------
__global__ __launch_bounds__(256) void ln_kernel(
    const float* __restrict__ hs, const float* __restrict__ g, const float* __restrict__ be,
    short* __restrict__ n16, float* __restrict__ surprise)
{
  int row = blockIdx.x, tid = threadIdx.x;
  long base = (long)row * H;
  float4 x = ((const float4*)(hs + base))[tid];
  float s1 = x.x + x.y + x.z + x.w;
  float s2 = x.x*x.x + x.y*x.y + x.z*x.z + x.w*x.w;
  __shared__ float r1[4], r2[4], r3[4];
  int w = tid >> 6, lane = tid & 63;
  for (int o = 32; o; o >>= 1){ s1 += __shfl_down(s1, o); s2 += __shfl_down(s2, o); }
  if (lane == 0){ r1[w] = s1; r2[w] = s2; }
  __syncthreads();
  float S1 = r1[0]+r1[1]+r1[2]+r1[3];
  float S2 = r2[0]+r2[1]+r2[2]+r2[3];
  float mean = S1 * (1.0f/H);
  float var  = S2 * (1.0f/H) - mean*mean;
  float rinv = rsqrtf(var + 1e-12f);
  float4 gg = ((const float4*)g)[tid];
  float4 bb = ((const float4*)be)[tid];
  float4 n;
  n.x = (x.x-mean)*rinv*gg.x + bb.x;
  n.y = (x.y-mean)*rinv*gg.y + bb.y;
  n.z = (x.z-mean)*rinv*gg.z + bb.z;
  n.w = (x.w-mean)*rinv*gg.w + bb.w;
  float sa = fabsf(n.x)+fabsf(n.y)+fabsf(n.z)+fabsf(n.w);
  for (int o = 32; o; o >>= 1) sa += __shfl_down(sa, o);
  if (lane == 0) r3[w] = sa;
  __syncthreads();
  if (tid == 0) surprise[row] = (r3[0]+r3[1]+r3[2]+r3[3]) * (1.0f/H);
  short4 h4;
  h4.x = f2h(n.x); h4.y = f2h(n.y); h4.z = f2h(n.z); h4.w = f2h(n.w);
  ((short4*)(n16 + base))[tid] = h4;
}

// ---------------- top-K level 1: per-256-chunk bitonic sort, emit top-64 ----------------
// blocks 0..31: surprise (max). blocks 32..47: importance (min, key inverted).
// packed = (key32 << 32) | (8191 - idx): desc order == (val desc, idx asc) == jax top_k.
__global__ __launch_bounds__(256) void topk_local(
    const float* __restrict__ surprise, const float* __restrict__ imp,
    unsigned long long* __restrict__ cand_s, unsigned long long* __restrict__ cand_i)
{
  __shared__ unsigned long long s[256];
  int b = blockIdx.x, tid = threadIdx.x;
  int maxmode = (b < 32);
  int gidx = maxmode ? (b*256 + tid) : ((b-32)*256 + tid);
  float x = maxmode ? surprise[gidx] : imp[gidx];
  unsigned k = fkey_of(x);
  if (!maxmode) k = ~k;
  s[tid] = ((unsigned long long)k << 32) | (unsigned)(8191 - gidx);
  __syncthreads();
  for (int kk = 2; kk <= 256; kk <<= 1)
    for (int j = kk >> 1; j > 0; j >>= 1){
      int i = tid, ixj = i ^ j;
      if (ixj > i){
        bool asc = ((i & kk) == 0);
        unsigned long long a = s[i], c = s[ixj];
        if ((a < c) == asc){ s[i] = c; s[ixj] = a; }   // descending overall
      }
      __syncthreads();
    }
  if (tid < 64){
    if (maxmode) cand_s[b*64 + tid] = s[tid];
    else         cand_i[(b-32)*64 + tid] = s[tid];
  }
}

// ---------------- top-K level 2: merge candidates via bitonic sort ----------------
// block 0: 2048 surprise candidates -> top_vals/top_idx. block 1: 1024 -> slots.
__global__ __launch_bounds__(256) void topk_merge(
    const unsigned long long* __restrict__ cand_s, const unsigned long long* __restrict__ cand_i,
    float* __restrict__ top_vals, int* __restrict__ top_idx, int* __restrict__ slots)
{
  __shared__ unsigned long long s[2048];
  int tid = threadIdx.x;
  int N = (blockIdx.x == 0) ? 2048 : 1024;
  const unsigned long long* src = (blockIdx.x == 0) ? cand_s : cand_i;
  for (int i = tid; i < N; i += 256) s[i] = src[i];
  __syncthreads();
  for (int kk = 2; kk <= N; kk <<= 1)
    for (int j = kk >> 1; j > 0; j >>= 1){
      for (int i = tid; i < N; i += 256){
        int ixj = i ^ j;
        if (ixj > i){
          bool asc = ((i & kk) == 0);
          unsigned long long a = s[i], c = s[ixj];
          if ((a < c) == asc){ s[i] = c; s[ixj] = a; }
        }
      }
      __syncthreads();
    }
  if (tid < 64){
    unsigned long long p = s[tid];
    int gi = 8191 - (int)(p & 0xffffffffu);
    if (blockIdx.x == 0){
      top_vals[tid] = val_of((unsigned)(p >> 32));
      top_idx[tid] = gi;
    } else {
      slots[tid] = gi;
    }
  }
}

// ---------------- fused prep: mem->m16+memT, Wq->hi/lo split (as-is layout), Wo->fp16 ----------------
__global__ __launch_bounds__(256) void prep_all_kernel(
    const float* __restrict__ mem, const float* __restrict__ Wq, const float* __restrict__ Wo,
    short* __restrict__ m16, short* __restrict__ memT,
    short* __restrict__ wq_h, short* __restrict__ wq_l, short* __restrict__ wo16)
{
  __shared__ __align__(16) short t[64][66];
  int b = blockIdx.x, tid = threadIdx.x;
  if (b < 1024){
    // mem fp32 64x64 tile -> m16 (row-major) + memT (transposed)
    int r0 = (b >> 4) * 64, c0 = (b & 15) * 64;
    #pragma unroll
    for (int k = 0; k < 4; ++k){
      int idx = k*256 + tid;
      int r = idx >> 4, c4 = (idx & 15) * 4;
      float4 x = *(const float4*)&mem[(long)(r0+r)*H + c0 + c4];
      short4 h;
      h.x = f2h(x.x); h.y = f2h(x.y); h.z = f2h(x.z); h.w = f2h(x.w);
      *(short4*)&m16[(long)(r0+r)*H + c0 + c4] = h;
      t[r][c4] = h.x; t[r][c4+1] = h.y; t[r][c4+2] = h.z; t[r][c4+3] = h.w;
    }
    __syncthreads();
    #pragma unroll
    for (int k = 0; k < 4; ++k){
      int idx = k*256 + tid;
      int c = idx >> 4, r4 = (idx & 15) * 4;
      short4 h;
      h.x = t[r4][c]; h.y = t[r4+1][c]; h.z = t[r4+2][c]; h.w = t[r4+3][c];
      *(short4*)&memT[(long)(c0+c)*MMEM + r0 + r4] = h;
    }
  } else if (b < 2048){
    // Wq elementwise fp16 hi/lo split, native [o][h] layout (B-operand of Q GEMM
    // contracts over its 2nd index = h, matching einsum "bsh,oh->bso")
    long i = (long)(b - 1024) * 256 + tid;
    float4 x = ((const float4*)Wq)[i];
    short4 h, l;
    h.x = f2h(x.x); l.x = f2h(x.x - h2f(h.x));
    h.y = f2h(x.y); l.y = f2h(x.y - h2f(h.y));
    h.z = f2h(x.z); l.z = f2h(x.z - h2f(h.z));
    h.w = f2h(x.w); l.w = f2h(x.w - h2f(h.w));
    ((short4*)wq_h)[i] = h;
    ((short4*)wq_l)[i] = l;
  } else {
    long i = (long)(b - 2048) * 256 + tid;
    float4 x = ((const float4*)Wo)[i];
    short4 h;
    h.x = f2h(x.x); h.y = f2h(x.y); h.z = f2h(x.z); h.w = f2h(x.w);
    ((short4*)wo16)[i] = h;
  }
}

// ---------------- top-K writes: recompute LN of selected rows, patch m16 + memT ----------------
__global__ __launch_bounds__(256) void update_kernel(
    const float* __restrict__ top_vals, const int* __restrict__ top_idx, const int* __restrict__ slots,
    const float* __restrict__ hs, const float* __restrict__ g, const float* __restrict__ be,
    short* __restrict__ m16, short* __restrict__ memT)
{
  int i = blockIdx.x;
  if (top_vals[i] <= FTHRESH) return;
  int s = slots[i], r = top_idx[i];
  int tid = threadIdx.x, w = tid >> 6, lane = tid & 63;
  long base = (long)r * H;
  float4 x = ((const float4*)(hs + base))[tid];
  float s1 = x.x + x.y + x.z + x.w;
  float s2 = x.x*x.x + x.y*x.y + x.z*x.z + x.w*x.w;
  __shared__ float r1[4], r2[4];
  for (int o = 32; o; o >>= 1){ s1 += __shfl_down(s1, o); s2 += __shfl_down(s2, o); }
  if (lane == 0){ r1[w] = s1; r2[w] = s2; }
  __syncthreads();
  float S1 = r1[0]+r1[1]+r1[2]+r1[3];
  float S2 = r2[0]+r2[1]+r2[2]+r2[3];
  float mean = S1 * (1.0f/H);
  float var  = S2 * (1.0f/H) - mean*mean;
  float rinv = rsqrtf(var + 1e-12f);
  float4 gg = ((const float4*)g)[tid];
  float4 bb = ((const float4*)be)[tid];
  short4 h4;
  h4.x = f2h((x.x-mean)*rinv*gg.x + bb.x);
  h4.y = f2h((x.y-mean)*rinv*gg.y + bb.y);
  h4.z = f2h((x.z-mean)*rinv*gg.z + bb.z);
  h4.w = f2h((x.w-mean)*rinv*gg.w + bb.w);
  ((short4*)(m16 + (long)s*H))[tid] = h4;
  long c4 = (long)tid * 4;
  memT[(c4+0)*MMEM + s] = h4.x;
  memT[(c4+1)*MMEM + s] = h4.y;
  memT[(c4+2)*MMEM + s] = h4.z;
  memT[(c4+3)*MMEM + s] = h4.w;
}

// ---------------- biasM[m] = bq . mem_upd[m] (reads patched m16) ----------------
__global__ __launch_bounds__(256) void bias_kernel(
    const float* __restrict__ bq, const short* __restrict__ m16, float* __restrict__ biasM)
{
  int tid = threadIdx.x, w = tid >> 6, lane = tid & 63;
  int m = blockIdx.x*4 + w;
  const short* ph = m16 + (long)m*H;
  float s = 0.f;
  for (int j = 0; j < 16; ++j){
    int h = lane + j*64;
    s += bq[h] * h2f(ph[h]);
  }
  for (int o = 32; o; o >>= 1) s += __shfl_down(s, o);
  if (lane == 0) biasM[m] = s;
}

// ---------------- 128x128-tile fp16 GEMM: C[M][N] = A[M][K] * B[N][K]^T ----------------
// m97 recipe (BK=64, global_load_lds w16, 2 barriers/K-block) + XOR-8 LDS swizzle
// (chunk pos ^= row&7 on global source AND ds_read side -> conflicts measured 0).
// SPLIT: 0 = A,B single f16 (1 MFMA); 2 = A single, B fp16 hi/lo (2 MFMA compensated).
// MODE 1: C+biasN -> fp16.  2: C -> fp16.  3: C+resid+biasN -> fp32.
template<int SPLIT, int MODE>
__global__ __launch_bounds__(256) void gemm128(
    const short* __restrict__ A,
    const short* __restrict__ Bh, const short* __restrict__ Bl,
    int K, int N,
    short* __restrict__ O1,
    float* __restrict__ Of, const float* __restrict__ resid, const float* __restrict__ biasN)
{
  __shared__ short sA[128*64];
  __shared__ short sBh[128*64];
  __shared__ short sBl[SPLIT ? 128*64 : 64];
  int tid = threadIdx.x, w = tid >> 6, lane = tid & 63, ln = lane & 15, quad = lane >> 4;
  int wr = w >> 1, wc = w & 1;
  long m0 = (long)blockIdx.y * 128, n0 = (long)blockIdx.x * 128;
  long Kl = K;
  vf4 acc[4][4];
  #pragma unroll
  for (int i = 0; i < 4; ++i) for (int j = 0; j < 4; ++j) for (int r = 0; r < 4; ++r) acc[i][j][r] = 0.0f;

  for (long kk = 0; kk < Kl; kk += 64){
    #pragma unroll
    for (int j = 0; j < 4; ++j){
      int f = (w*4 + j)*64 + lane;            // 16B-chunk id in [0,1024)
      int row = f >> 3, c8 = f & 7;
      long go = kk + (long)((c8 ^ (row & 7)) * 8);   // XOR-swizzled source chunk
      gload_lds16(A  + (m0+row)*Kl + go, sA  + (w*4+j)*512);
      gload_lds16(Bh + (n0+row)*Kl + go, sBh + (w*4+j)*512);
      if (SPLIT) gload_lds16(Bl + (n0+row)*Kl + go, sBl + (w*4+j)*512);
    }
    __syncthreads();
    #pragma unroll
    for (int ks = 0; ks < 64; ks += 32){
      int cbase = (ks >> 3) + quad;
      half8 bh[4], bl[4];
      #pragma unroll
      for (int j = 0; j < 4; ++j){
        int rb = wc*64 + j*16 + ln;
        int cb = cbase ^ (rb & 7);
        bh[j] = *(const half8*)&sBh[rb*64 + cb*8];
        if (SPLIT) bl[j] = *(const half8*)&sBl[rb*64 + cb*8];
      }
      #pragma unroll
      for (int i = 0; i < 4; ++i){
        int ra = wr*64 + i*16 + ln;
        int ca = cbase ^ (ra & 7);
        half8 a = *(const half8*)&sA[ra*64 + ca*8];
        #pragma unroll
        for (int j = 0; j < 4; ++j){
          acc[i][j] = __builtin_amdgcn_mfma_f32_16x16x32_f16(a, bh[j], acc[i][j], 0, 0, 0);
          if (SPLIT)
            acc[i][j] = __builtin_amdgcn_mfma_f32_16x16x32_f16(a, bl[j], acc[i][j], 0, 0, 0);
        }
      }
    }
    __syncthreads();
  }

  #pragma unroll
  for (int i = 0; i < 4; ++i){
    #pragma unroll
    for (int j = 0; j < 4; ++j){
      #pragma unroll
      for (int r = 0; r < 4; ++r){
        long row = m0 + wr*64 + i*16 + quad*4 + r;   // C/D: row=quad*4+reg, col=lane&15
        long col = n0 + wc*64 + j*16 + ln;
        float v = acc[i][j][r];
        if (MODE == 1){
          O1[row*(long)N + col] = f2h(v + biasN[col]);
        } else if (MODE == 2){
          O1[row*(long)N + col] = f2h(v);
        } else {
          Of[row*(long)N + col] = v + resid[row*(long)N + col] + biasN[col];
        }
      }
    }
  }
}

// ---------------- row softmax in-place: sim fp16 [NTOK][MMEM] -> P fp16 ----------------
__global__ __launch_bounds__(256) void softmax_kernel(short* __restrict__ simP)
{
  long row = blockIdx.x;
  int tid = threadIdx.x, w = tid >> 6, lane = tid & 63;
  half8* ptr = (half8*)(simP + row*MMEM);
  float xf[16];
  float mx = -1e30f;
  #pragma unroll
  for (int j = 0; j < 2; ++j){
    half8 x = ptr[tid + j*256];
    #pragma unroll
    for (int e = 0; e < 8; ++e){ float f = (float)x[e]; xf[j*8+e] = f; mx = fmaxf(mx, f); }
  }
  for (int o = 32; o; o >>= 1) mx = fmaxf(mx, __shfl_xor(mx, o));
  __shared__ float rmax[4], rsum[4];
  if (lane == 0) rmax[w] = mx;
  __syncthreads();
  mx = fmaxf(fmaxf(rmax[0], rmax[1]), fmaxf(rmax[2], rmax[3]));
  float p[16], s = 0.f;
  #pragma unroll
  for (int k = 0; k < 16; ++k){ p[k] = __expf(xf[k] - mx); s += p[k]; }
  for (int o = 32; o; o >>= 1) s += __shfl_xor(s, o);
  if (lane == 0) rsum[w] = s;
  __syncthreads();
  float inv = 1.0f / (rsum[0]+rsum[1]+rsum[2]+rsum[3]);
  #pragma unroll
  for (int j = 0; j < 2; ++j){
    half8 o8;
    #pragma unroll
    for (int e = 0; e < 8; ++e) o8[e] = (_Float16)(p[j*8+e] * inv);
    ptr[tid + j*256] = o8;
  }
}

extern "C" void kernel_launch(void* const* d_in, const int* in_sizes, int n_in,
                              void* d_out, int out_size, void* d_ws, size_t ws_size,
                              hipStream_t stream)
{
  const float* hs  = (const float*)d_in[0];
  const float* gam = (const float*)d_in[1];
  const float* bet = (const float*)d_in[2];
  const float* Wq  = (const float*)d_in[3];
  const float* bq  = (const float*)d_in[4];
  const float* Wo  = (const float*)d_in[5];
  const float* bo  = (const float*)d_in[6];
  const float* mem = (const float*)d_in[7];
  const float* imp = (const float*)d_in[8];
  float* out = (float*)d_out;

  char* ws = (char*)d_ws;
  short* n16   = (short*)(ws);                   // [0,16)   fp16 norm
  short* q16   = (short*)(ws + (16ull<<20));     // [16,32)  fp16 Q = norm@Wq^T
  short* m16   = (short*)(ws + (32ull<<20));     // [32,40)  fp16 mem (patched)
  short* memT  = (short*)(ws + (40ull<<20));     // [40,48)  mem_upd^T fp16 (patched)
  short* simP  = (short*)(ws + (48ull<<20));     // [48,112) fp16 logits, softmax in-place -> P
  short* retr  = (short*)(ws + (112ull<<20));    // [112,128)
  short* wq_h  = (short*)(ws + (128ull<<20));    // [128,130) Wq fp16 hi, native [o][h]
  short* wq_l  = (short*)(ws + (130ull<<20));    // [130,132) Wq fp16 lo
  short* wo16  = (short*)(ws + (132ull<<20));    // [132,134)
  char*  tail  = ws + (134ull<<20);
  float* biasM    = (float*)tail;
  float* surprise = (float*)(tail + (64<<10));
  float* top_vals = (float*)(tail + (128<<10));
  int*   top_idx  = (int*)  (tail + (129<<10));
  int*   slots    = (int*)  (tail + (130<<10));
  unsigned long long* cand_s = (unsigned long long*)(tail + (132<<10));  // 16 KB
  unsigned long long* cand_i = (unsigned long long*)(tail + (148<<10));  // 8 KB

  ln_kernel<<<NTOK, 256, 0, stream>>>(hs, gam, bet, n16, surprise);
  topk_local<<<48, 256, 0, stream>>>(surprise, imp, cand_s, cand_i);
  topk_merge<<<2, 256, 0, stream>>>(cand_s, cand_i, top_vals, top_idx, slots);
  prep_all_kernel<<<3072, 256, 0, stream>>>(mem, Wq, Wo, m16, memT, wq_h, wq_l, wo16);
  update_kernel<<<KTOP, 256, 0, stream>>>(top_vals, top_idx, slots, hs, gam, bet, m16, memT);
  bias_kernel<<<1024, 256, 0, stream>>>(bq, m16, biasM);
  // Q = norm @ Wq^T  (B = Wq native layout, split hi/lo), out fp16
  gemm128<2,2><<<dim3(8,64), 256, 0, stream>>>(
      n16, wq_h, wq_l, H, H, q16, nullptr, nullptr, nullptr);
  // sim = Q @ m16^T + biasM  (plain f16, 1 MFMA/elem), out fp16
  gemm128<0,1><<<dim3(32,64), 256, 0, stream>>>(
      q16, m16, m16, H, MMEM, simP, nullptr, nullptr, biasM);
  // softmax rows in-place -> P fp16 (normalized)
  softmax_kernel<<<NTOK, 256, 0, stream>>>(simP);
  // retr = P @ memT^T  (plain f16)
  gemm128<0,2><<<dim3(8,64), 256, 0, stream>>>(
      simP, memT, memT, MMEM, H, retr, nullptr, nullptr, nullptr);
  // out = hidden + retr @ Wo^T + bo
  gemm128<0,3><<<dim3(8,64), 256, 0, stream>>>(
      retr, wo16, wo16, H, H, nullptr, out, hs, bo);
}